// Round 3
// baseline (10042.123 us; speedup 1.0000x reference)
//
#include <hip/hip_runtime.h>

#define NN1 60000
#define EE1 600000
#define NN2 20000
#define EE2 150000
#define AA  60000

__device__ __forceinline__ float sigf(float x){ return 1.f/(1.f+expf(-x)); }
__device__ __forceinline__ unsigned fkey(float f){
  unsigned u = __float_as_uint(f);
  return (u & 0x80000000u) ? ~u : (u | 0x80000000u);
}
__device__ __forceinline__ float funkey(unsigned k){
  unsigned u = (k & 0x80000000u) ? (k ^ 0x80000000u) : ~k;
  return __uint_as_float(u);
}

// ---------- elementwise ----------
__global__ void k_relu(float* a, int n){
  int i = blockIdx.x*blockDim.x + threadIdx.x;
  if (i < n) a[i] = fmaxf(a[i], 0.f);
}
__global__ void k_copy(const float* __restrict__ a, float* __restrict__ o, int n){
  int i = blockIdx.x*blockDim.x + threadIdx.x;
  if (i < n) o[i] = a[i];
}

// ---------- edge type: first-argmax over edge_attr[:, :4] ----------
__global__ void k_etype(const float* __restrict__ ea, int* __restrict__ etype, int E){
  int e = blockIdx.x*blockDim.x + threadIdx.x;
  if (e >= E) return;
  const float* p = ea + (size_t)e*10;
  float best = p[0]; int bi = 0;
  #pragma unroll
  for (int k = 1; k < 4; ++k){ float v = p[k]; if (v > best){ best = v; bi = k; } }
  etype[e] = bi;
}

__global__ void k_coeff(const float* __restrict__ nt, const int* __restrict__ node_type,
                        float* __restrict__ coeff, int N){
  int n = blockIdx.x*blockDim.x + threadIdx.x;
  if (n < N) coeff[n] = nt[node_type[n]];
}

// ---------- single-type transform: tr[n][d] = sum_c h[n][c]*W[c][d] ----------
// block = 256 (4 node-slots x 64 channels); W[c][d] held in 64 VGPRs per thread
__global__ void k_transform1(const float* __restrict__ h, const float* __restrict__ W,
                             float* __restrict__ tr, int N){
  int d = threadIdx.x & 63;
  int sub = threadIdx.x >> 6;
  float wreg[64];
  #pragma unroll
  for (int c = 0; c < 64; ++c) wreg[c] = W[c*64 + d];
  for (int n = blockIdx.x*4 + sub; n < N; n += gridDim.x*4){
    const float* hr = h + (size_t)n*64;
    float acc = 0.f;
    #pragma unroll
    for (int c = 0; c < 64; ++c) acc = fmaf(hr[c], wreg[c], acc);
    tr[(size_t)n*64 + d] = acc;
  }
}

// ---------- message + scatter-add for one edge type ----------
// one wave (64 lanes) per edge; wave-uniform early exit when etype!=twant
__global__ void k_aggregate(const float* __restrict__ tr, const int* __restrict__ src,
                            const int* __restrict__ dst, const int* __restrict__ etype,
                            int twant, const float* __restrict__ coeff,
                            float* __restrict__ aggr, int E){
  int i = blockIdx.x*blockDim.x + threadIdx.x;  // up to 38.4M, fits int32
  if (i >= E*64) return;
  int e = i >> 6, c = i & 63;
  if (etype && etype[e] != twant) return;
  int s = src[e];
  float v = tr[(size_t)s*64 + c];
  if (coeff) v *= coeff[s];
  atomicAdd(&aggr[(size_t)dst[e]*64 + c], v);
}

// ---------- GRU update: h = (1-z)*n + z*h ----------
// block = 192 threads; thread j owns gate-row j of wih/whh (64 weights each in VGPRs)
__global__ void k_gru(const float* __restrict__ aggr, float* __restrict__ h,
                      const float* __restrict__ wih, const float* __restrict__ whh,
                      const float* __restrict__ bih, const float* __restrict__ bhh, int N){
  int j = threadIdx.x;
  float wi[64], wh[64];
  #pragma unroll
  for (int c = 0; c < 64; ++c){ wi[c] = wih[j*64 + c]; wh[c] = whh[j*64 + c]; }
  float bi = bih[j], bh = bhh[j];
  __shared__ float gi_s[192], gh_s[192];
  for (int n = blockIdx.x; n < N; n += gridDim.x){
    const float* mr = aggr + (size_t)n*64;
    const float* hr = h + (size_t)n*64;
    float ai = bi, ah = bh;
    #pragma unroll
    for (int c = 0; c < 64; ++c){ ai = fmaf(mr[c], wi[c], ai); ah = fmaf(hr[c], wh[c], ah); }
    gi_s[j] = ai; gh_s[j] = ah;
    __syncthreads();
    if (j < 64){
      float r  = sigf(gi_s[j]      + gh_s[j]);
      float z  = sigf(gi_s[64+j]   + gh_s[64+j]);
      float nn = tanhf(gi_s[128+j] + r*gh_s[128+j]);
      h[(size_t)n*64 + j] = (1.f - z)*nn + z*hr[j];
    }
    __syncthreads();
  }
}

// ---------- batch norm over nodes (64 channels, biased var) ----------
__global__ void k_bnstats(const float* __restrict__ h, float* __restrict__ stats, int N){
  int c = threadIdx.x & 63;
  int g = threadIdx.x >> 6;   // 0..3
  float s = 0.f, s2 = 0.f;
  for (int n = blockIdx.x*4 + g; n < N; n += gridDim.x*4){
    float v = h[(size_t)n*64 + c]; s += v; s2 += v*v;
  }
  __shared__ float sh[4][64], sh2[4][64];
  sh[g][c] = s; sh2[g][c] = s2;
  __syncthreads();
  if (g == 0){
    float ts = sh[0][c]+sh[1][c]+sh[2][c]+sh[3][c];
    float t2 = sh2[0][c]+sh2[1][c]+sh2[2][c]+sh2[3][c];
    atomicAdd(&stats[c], ts); atomicAdd(&stats[64+c], t2);
  }
}
__global__ void k_bnapply(float* __restrict__ h, const float* __restrict__ stats,
                          const float* __restrict__ g, const float* __restrict__ b,
                          int N, int relu){
  int i = blockIdx.x*blockDim.x + threadIdx.x;
  if (i >= N*64) return;
  int c = i & 63;
  float inv = 1.f/(float)N;
  float mean = stats[c]*inv;
  float var  = stats[64+c]*inv - mean*mean;
  float y = (h[i]-mean)*rsqrtf(var + 1e-5f)*g[c] + b[c];
  if (relu) y = fmaxf(y, 0.f);
  h[i] = y;
}

// ---------- avg_pool ----------
__global__ void k_pool_acc(const float* __restrict__ h, const int* __restrict__ asrc,
                           const int* __restrict__ adst, float* __restrict__ h2,
                           float* __restrict__ cnt, int A){
  int i = blockIdx.x*blockDim.x + threadIdx.x;
  if (i >= A*64) return;
  int a = i >> 6, c = i & 63;
  int s = asrc[a], d = adst[a];
  atomicAdd(&h2[(size_t)d*64 + c], h[(size_t)s*64 + c]);
  if (c == 0) atomicAdd(&cnt[d], 1.f);
}
__global__ void k_pool_div(float* __restrict__ h2, const float* __restrict__ cnt, int N){
  int i = blockIdx.x*blockDim.x + threadIdx.x;
  if (i >= N*64) return;
  h2[i] = h2[i] / fmaxf(cnt[i >> 6], 1.f);
}

// ---------- set2set ----------
__global__ void k_lstm(const float* __restrict__ inp, float* __restrict__ hv, float* __restrict__ cv,
                       const float* __restrict__ wih, const float* __restrict__ whh,
                       const float* __restrict__ bias, int IN){
  int b = blockIdx.x, j = threadIdx.x;    // 256 threads = 256 gate rows
  __shared__ float is[128], hs[64], gs[256];
  if (j < IN) is[j] = inp[(size_t)b*IN + j];
  if (j < 64) hs[j] = hv[(size_t)b*64 + j];
  __syncthreads();
  float acc = bias[j];
  const float* wr = wih + (size_t)j*IN;
  for (int k = 0; k < IN; ++k) acc = fmaf(wr[k], is[k], acc);
  const float* w2 = whh + (size_t)j*64;
  #pragma unroll
  for (int k = 0; k < 64; ++k) acc = fmaf(w2[k], hs[k], acc);
  gs[j] = acc;
  __syncthreads();
  if (j < 64){
    float ig = sigf(gs[j]);
    float fg = sigf(gs[64+j]);
    float gg = tanhf(gs[128+j]);
    float og = sigf(gs[192+j]);
    float cn = fg*cv[(size_t)b*64+j] + ig*gg;
    cv[(size_t)b*64+j] = cn;
    hv[(size_t)b*64+j] = og*tanhf(cn);
  }
}
__global__ void k_attn_e(const float* __restrict__ x, const float* __restrict__ q,
                         const int* __restrict__ batch, float* __restrict__ e,
                         unsigned* __restrict__ emax, int N){
  int w = threadIdx.x >> 6, lane = threadIdx.x & 63;
  int n = blockIdx.x*4 + w;
  if (n >= N) return;
  int b = batch[n];
  float v = x[(size_t)n*64 + lane]*q[(size_t)b*64 + lane];
  for (int o = 32; o; o >>= 1) v += __shfl_down(v, o);
  if (lane == 0){ e[n] = v; atomicMax(&emax[b], fkey(v)); }
}
__global__ void k_attn_ex(const float* __restrict__ e, const unsigned* __restrict__ emax,
                          const int* __restrict__ batch, float* __restrict__ ex,
                          float* __restrict__ denom, int N){
  int n = blockIdx.x*blockDim.x + threadIdx.x;
  if (n >= N) return;
  int b = batch[n];
  float v = expf(e[n] - funkey(emax[b]));
  ex[n] = v;
  atomicAdd(&denom[b], v);
}
__global__ void k_qstar_prep(const float* __restrict__ h1, float* __restrict__ qstar){
  int i = blockIdx.x*blockDim.x + threadIdx.x;
  if (i >= 256*128) return;
  int b = i >> 7, c = i & 127;
  qstar[i] = (c < 64) ? h1[b*64 + c] : 0.f;
}
__global__ void k_attn_r(const float* __restrict__ x, const float* __restrict__ ex,
                         const float* __restrict__ denom, const int* __restrict__ batch,
                         float* __restrict__ qstar, int N){
  int w = threadIdx.x >> 6, lane = threadIdx.x & 63;
  int n = blockIdx.x*4 + w;
  if (n >= N) return;
  int b = batch[n];
  float a = ex[n]/denom[b];
  atomicAdd(&qstar[b*128 + 64 + lane], a*x[(size_t)n*64 + lane]);
}

// ---------- head ----------
__global__ void k_concat(const float* __restrict__ x1, const float* __restrict__ x2,
                         float* __restrict__ z){
  int i = blockIdx.x*blockDim.x + threadIdx.x;
  if (i >= 256*256) return;
  int b = i >> 8, c = i & 255;
  z[i] = (c < 128) ? x1[b*128 + c] : x2[b*128 + (c - 128)];
}
__global__ void k_bn_small(float* __restrict__ X, const float* __restrict__ g,
                           const float* __restrict__ b, int Bn, int F, int relu){
  int f = threadIdx.x;
  if (f >= F) return;
  float s = 0.f, s2 = 0.f;
  for (int i = 0; i < Bn; ++i){ float v = X[i*F + f]; s += v; s2 += v*v; }
  float mean = s/(float)Bn;
  float var  = s2/(float)Bn - mean*mean;
  float sc = rsqrtf(var + 1e-5f)*g[f];
  float bb = b[f];
  for (int i = 0; i < Bn; ++i){
    float y = (X[i*F + f] - mean)*sc + bb;
    if (relu) y = fmaxf(y, 0.f);
    X[i*F + f] = y;
  }
}
__global__ void k_fc(const float* __restrict__ X, const float* __restrict__ W,
                     const float* __restrict__ bias, float* __restrict__ Y, int K, int F){
  int b = blockIdx.x, f = threadIdx.x;
  if (f >= F) return;
  const float* xr = X + (size_t)b*K;
  const float* wr = W + (size_t)f*K;
  float acc = bias[f];
  for (int k = 0; k < K; ++k) acc = fmaf(xr[k], wr[k], acc);
  Y[b*F + f] = acc;
}
__global__ void k_fc_out(const float* __restrict__ z2, const float* __restrict__ w,
                         const float* __restrict__ bias, float* __restrict__ out){
  int b = blockIdx.x*blockDim.x + threadIdx.x;
  if (b >= 256) return;
  float acc = bias[0];
  #pragma unroll
  for (int k = 0; k < 64; ++k) acc = fmaf(z2[b*64 + k], w[k], acc);
  out[b] = acc;
}

extern "C" void kernel_launch(void* const* d_in, const int* in_sizes, int n_in,
                              void* d_out, int out_size, void* d_ws, size_t ws_size,
                              hipStream_t stream) {
  const float* x_in     = (const float*)d_in[0];
  const float* edge_attr= (const float*)d_in[1];
  const float* conv_w   = (const float*)d_in[2];   // [5][3][4][64][64]
  const float* conv_wih = (const float*)d_in[3];   // [5][192][64]
  const float* conv_whh = (const float*)d_in[4];
  const float* conv_bih = (const float*)d_in[5];   // [5][192]
  const float* conv_bhh = (const float*)d_in[6];
  const float* conv_nt  = (const float*)d_in[7];   // [5][9]
  const float* s1_wih0 = (const float*)d_in[8];
  const float* s1_whh0 = (const float*)d_in[9];
  const float* s1_b0   = (const float*)d_in[10];
  const float* s1_wih1 = (const float*)d_in[11];
  const float* s1_whh1 = (const float*)d_in[12];
  const float* s1_b1   = (const float*)d_in[13];
  const float* s2_wih0 = (const float*)d_in[14];
  const float* s2_whh0 = (const float*)d_in[15];
  const float* s2_b0   = (const float*)d_in[16];
  const float* s2_wih1 = (const float*)d_in[17];
  const float* s2_whh1 = (const float*)d_in[18];
  const float* s2_b1   = (const float*)d_in[19];
  const float* bn_g    = (const float*)d_in[20];
  const float* bn_b    = (const float*)d_in[21];
  const float* prebn_g = (const float*)d_in[22];
  const float* prebn_b = (const float*)d_in[23];
  const float* fc_w0   = (const float*)d_in[24];
  const float* fc_b0   = (const float*)d_in[25];
  const float* fc_w1   = (const float*)d_in[26];
  const float* fc_b1   = (const float*)d_in[27];
  const float* fc_w2   = (const float*)d_in[28];
  const float* fc_b2   = (const float*)d_in[29];
  const float* fcbn_g0 = (const float*)d_in[30];
  const float* fcbn_b0 = (const float*)d_in[31];
  const float* fcbn_g1 = (const float*)d_in[32];
  const float* fcbn_b1 = (const float*)d_in[33];
  const int* edge_index   = (const int*)d_in[34];
  const int* node_type    = (const int*)d_in[35];
  const int* batch        = (const int*)d_in[36];
  const int* assign_src   = (const int*)d_in[37];
  const int* assign_dst   = (const int*)d_in[38];
  const int* edge_index_2 = (const int*)d_in[39];
  const int* batch_2      = (const int*)d_in[40];
  (void)in_sizes; (void)n_in; (void)out_size; (void)ws_size;

  // ---- workspace layout (f32), ~56 MB total ----
  float* Wp = (float*)d_ws;
  size_t o = 0;
  auto alloc = [&](size_t n){ float* p = Wp + o; o += n; return p; };
  float*  h     = alloc((size_t)NN1*64);      // 15.36 MB
  float*  tr    = alloc((size_t)NN1*64);      // 15.36 MB (one edge-type at a time; reused at level 2)
  float*  aggr  = alloc((size_t)NN1*64);      // 15.36 MB (reused at level 2)
  int*    etype = (int*)alloc(EE1);           // 2.4 MB
  float*  coeff = alloc(NN1);
  float*  h2    = alloc((size_t)NN2*64);      // 5.12 MB
  float*  cnt   = alloc(NN2);
  float*  ebuf  = alloc(NN1);
  float*  exbuf = alloc(NN1);
  float*  qstar = alloc(256*128);   // qstar..cc1 contiguous: one memset zeroes all set2set state
  float*  hh0   = alloc(256*64);
  float*  cc0   = alloc(256*64);
  float*  hh1   = alloc(256*64);
  float*  cc1   = alloc(256*64);
  unsigned* emaxu = (unsigned*)alloc(256);  // emaxu+denom contiguous (2048 B memset)
  float*  denom = alloc(256);
  float*  x1    = alloc(256*128);
  float*  x2    = alloc(256*128);
  float*  z     = alloc(256*256);
  float*  z1    = alloc(256*128);
  float*  z2    = alloc(256*64);
  float*  stats = alloc(128);
  (void)o;

  const int* src1 = edge_index;
  const int* dst1 = edge_index + EE1;
  const int* src2 = edge_index_2;
  const int* dst2 = edge_index_2 + EE2;

  k_etype<<<(EE1+255)/256, 256, 0, stream>>>(edge_attr, etype, EE1);
  k_copy<<<(NN1*64+255)/256, 256, 0, stream>>>(x_in, h, NN1*64);

  // ---- level-1: 3x MGGC(L=3) + BN + ReLU ----
  for (int i = 0; i < 3; ++i){
    k_coeff<<<(NN1+255)/256, 256, 0, stream>>>(conv_nt + i*9, node_type, coeff, NN1);
    for (int l = 0; l < 3; ++l){
      hipMemsetAsync(aggr, 0, (size_t)NN1*64*sizeof(float), stream);
      for (int t = 0; t < 4; ++t){
        k_transform1<<<4096, 256, 0, stream>>>(h, conv_w + (size_t)((i*3+l)*4 + t)*4096, tr, NN1);
        k_aggregate<<<(EE1*64+255)/256, 256, 0, stream>>>(tr, src1, dst1, etype, t, coeff, aggr, EE1);
      }
      k_gru<<<4096, 192, 0, stream>>>(aggr, h,
          conv_wih + (size_t)i*12288, conv_whh + (size_t)i*12288,
          conv_bih + i*192, conv_bhh + i*192, NN1);
    }
    hipMemsetAsync(stats, 0, 128*sizeof(float), stream);
    k_bnstats<<<256, 256, 0, stream>>>(h, stats, NN1);
    k_bnapply<<<(NN1*64+255)/256, 256, 0, stream>>>(h, stats, bn_g + i*64, bn_b + i*64, NN1, 1);
  }

  // ---- set2set helper ----
  auto set2set = [&](const float* xf, const int* bat, int Nn,
                     const float* wih0, const float* whh0, const float* b0,
                     const float* wih1, const float* whh1, const float* b1,
                     float* xout){
    hipMemsetAsync(qstar, 0, (size_t)(256*128 + 4*256*64)*sizeof(float), stream);
    for (int s = 0; s < 5; ++s){
      k_lstm<<<256, 256, 0, stream>>>(qstar, hh0, cc0, wih0, whh0, b0, 128);
      k_lstm<<<256, 256, 0, stream>>>(hh0, hh1, cc1, wih1, whh1, b1, 64);
      hipMemsetAsync(emaxu, 0, 2048, stream);   // emaxu[256] + denom[256]
      k_attn_e<<<(Nn+3)/4, 256, 0, stream>>>(xf, hh1, bat, ebuf, emaxu, Nn);
      k_attn_ex<<<(Nn+255)/256, 256, 0, stream>>>(ebuf, emaxu, bat, exbuf, denom, Nn);
      k_qstar_prep<<<128, 256, 0, stream>>>(hh1, qstar);
      k_attn_r<<<(Nn+3)/4, 256, 0, stream>>>(xf, exbuf, denom, bat, qstar, Nn);
    }
    k_copy<<<128, 256, 0, stream>>>(qstar, xout, 256*128);
  };

  set2set(h, batch, NN1, s1_wih0, s1_whh0, s1_b0, s1_wih1, s1_whh1, s1_b1, x1);

  // ---- avg_pool to level 2 ----
  hipMemsetAsync(h2, 0, (size_t)NN2*64*sizeof(float), stream);
  hipMemsetAsync(cnt, 0, (size_t)NN2*sizeof(float), stream);
  k_pool_acc<<<(AA*64+255)/256, 256, 0, stream>>>(h, assign_src, assign_dst, h2, cnt, AA);
  k_pool_div<<<(NN2*64+255)/256, 256, 0, stream>>>(h2, cnt, NN2);

  // ---- level-2: 2x relu(MGGC(L=3)), etype=0, coeff=1, no BN ----
  for (int L = 3; L < 5; ++L){
    for (int l = 0; l < 3; ++l){
      hipMemsetAsync(aggr, 0, (size_t)NN2*64*sizeof(float), stream);
      k_transform1<<<2048, 256, 0, stream>>>(h2, conv_w + (size_t)((L*3+l)*4)*4096, tr, NN2);
      k_aggregate<<<(EE2*64+255)/256, 256, 0, stream>>>(tr, src2, dst2, nullptr, 0, nullptr, aggr, EE2);
      k_gru<<<2048, 192, 0, stream>>>(aggr, h2,
          conv_wih + (size_t)L*12288, conv_whh + (size_t)L*12288,
          conv_bih + L*192, conv_bhh + L*192, NN2);
    }
    k_relu<<<(NN2*64+255)/256, 256, 0, stream>>>(h2, NN2*64);
  }

  set2set(h2, batch_2, NN2, s2_wih0, s2_whh0, s2_b0, s2_wih1, s2_whh1, s2_b1, x2);

  // ---- head ----
  k_concat<<<256, 256, 0, stream>>>(x1, x2, z);
  k_bn_small<<<1, 256, 0, stream>>>(z, prebn_g, prebn_b, 256, 256, 0);
  k_fc<<<256, 128, 0, stream>>>(z, fc_w0, fc_b0, z1, 256, 128);
  k_bn_small<<<1, 128, 0, stream>>>(z1, fcbn_g0, fcbn_b0, 256, 128, 1);
  k_fc<<<256, 64, 0, stream>>>(z1, fc_w1, fc_b1, z2, 128, 64);
  k_bn_small<<<1, 64, 0, stream>>>(z2, fcbn_g1, fcbn_b1, 256, 64, 1);
  k_fc_out<<<4, 64, 0, stream>>>(z2, fc_w2, fc_b2, (float*)d_out);
}

// Round 4
// 7704.118 us; speedup vs baseline: 1.3035x; 1.3035x over previous
//
#include <hip/hip_runtime.h>

#define NN1 60000
#define EE1 600000
#define NN2 20000
#define EE2 150000
#define AA  60000

__device__ __forceinline__ float sigf(float x){ return 1.f/(1.f+expf(-x)); }
__device__ __forceinline__ unsigned fkey(float f){
  unsigned u = __float_as_uint(f);
  return (u & 0x80000000u) ? ~u : (u | 0x80000000u);
}
__device__ __forceinline__ float funkey(unsigned k){
  unsigned u = (k & 0x80000000u) ? (k ^ 0x80000000u) : ~k;
  return __uint_as_float(u);
}

// ---------- elementwise ----------
__global__ void k_relu(float* a, int n){
  int i = blockIdx.x*blockDim.x + threadIdx.x;
  if (i < n) a[i] = fmaxf(a[i], 0.f);
}
__global__ void k_copy(const float* __restrict__ a, float* __restrict__ o, int n){
  int i = blockIdx.x*blockDim.x + threadIdx.x;
  if (i < n) o[i] = a[i];
}
__global__ void k_copyi(const int* __restrict__ a, int* __restrict__ o, int n){
  int i = blockIdx.x*blockDim.x + threadIdx.x;
  if (i < n) o[i] = a[i];
}

// ---------- edge type: first-argmax over edge_attr[:, :4] ----------
__global__ void k_etype(const float* __restrict__ ea, int* __restrict__ etype, int E){
  int e = blockIdx.x*blockDim.x + threadIdx.x;
  if (e >= E) return;
  const float* p = ea + (size_t)e*10;
  float best = p[0]; int bi = 0;
  #pragma unroll
  for (int k = 1; k < 4; ++k){ float v = p[k]; if (v > best){ best = v; bi = k; } }
  etype[e] = bi;
}

__global__ void k_coeff(const float* __restrict__ nt, const int* __restrict__ node_type,
                        float* __restrict__ coeff, int N){
  int n = blockIdx.x*blockDim.x + threadIdx.x;
  if (n < N) coeff[n] = nt[node_type[n]];
}

// ---------- CSR build: histogram / scan / scatter ----------
__global__ void k_hist(const int* __restrict__ dst, const int* __restrict__ etype,
                       int* __restrict__ cnt, int E, int N){
  int e = blockIdx.x*blockDim.x + threadIdx.x;
  if (e >= E) return;
  int t = etype ? etype[e] : 0;
  atomicAdd(&cnt[t*N + dst[e]], 1);
}
// hierarchical exclusive scan of cnt[0..M) -> R[0..M], chunk=1024
__global__ void k_chunksum(const int* __restrict__ cnt, int* __restrict__ csum, int M){
  __shared__ int sh[256];
  int base = blockIdx.x*1024;
  int s = 0;
  for (int i = threadIdx.x; i < 1024; i += 256){
    int idx = base + i;
    if (idx < M) s += cnt[idx];
  }
  sh[threadIdx.x] = s;
  __syncthreads();
  for (int o = 128; o; o >>= 1){
    if (threadIdx.x < o) sh[threadIdx.x] += sh[threadIdx.x + o];
    __syncthreads();
  }
  if (threadIdx.x == 0) csum[blockIdx.x] = sh[0];
}
__global__ void k_chunkscan(int* __restrict__ csum, int nchunk){
  if (threadIdx.x != 0 || blockIdx.x != 0) return;
  int run = 0;
  for (int b = 0; b < nchunk; ++b){ int t = csum[b]; csum[b] = run; run += t; }
  csum[nchunk] = run;
}
__global__ void k_chunkapply(const int* __restrict__ cnt, const int* __restrict__ csum,
                             int* __restrict__ R, int M){
  if (threadIdx.x != 0) return;
  int base = blockIdx.x*1024;
  int run = csum[blockIdx.x];
  for (int i = 0; i < 1024; ++i){
    int idx = base + i;
    if (idx >= M) break;
    R[idx] = run; run += cnt[idx];
  }
  if (base + 1024 >= M) R[M] = run;
}
__global__ void k_scatter(const int* __restrict__ src, const int* __restrict__ dst,
                          const int* __restrict__ etype, int* __restrict__ cur,
                          int* __restrict__ ep, int E, int N){
  int e = blockIdx.x*blockDim.x + threadIdx.x;
  if (e >= E) return;
  int t = etype ? etype[e] : 0;
  int pos = atomicAdd(&cur[t*N + dst[e]], 1);
  ep[pos] = src[e];
}

// ---------- transform: tr[n][d] = coeff[n] * sum_c h[n][c]*W[c][d] ----------
// block 256 = 4 node-slots x 64 channels; 64 weight VGPRs/thread; persistent grid
__global__ void k_transform(const float* __restrict__ h, const float* __restrict__ W,
                            const float* __restrict__ coeff, float* __restrict__ tr, int N){
  int d = threadIdx.x & 63;
  int sub = threadIdx.x >> 6;
  float wreg[64];
  #pragma unroll
  for (int c = 0; c < 64; ++c) wreg[c] = W[c*64 + d];
  for (int n = blockIdx.x*4 + sub; n < N; n += gridDim.x*4){
    const float4* hr = (const float4*)(h + (size_t)n*64);
    float acc = 0.f;
    #pragma unroll
    for (int c = 0; c < 16; ++c){
      float4 v = hr[c];
      acc = fmaf(v.x, wreg[4*c+0], acc);
      acc = fmaf(v.y, wreg[4*c+1], acc);
      acc = fmaf(v.z, wreg[4*c+2], acc);
      acc = fmaf(v.w, wreg[4*c+3], acc);
    }
    if (coeff) acc *= coeff[n];
    tr[(size_t)n*64 + d] = acc;
  }
}

// ---------- CSR aggregation sweep: one wave per dst node ----------
// R is pre-offset by t*N; batched edge-id loads broadcast via shuffle
__global__ void k_sweep(const float* __restrict__ tr, const int* __restrict__ R,
                        const int* __restrict__ ep, float* __restrict__ aggr,
                        int N, int first){
  int w = threadIdx.x >> 6, lane = threadIdx.x & 63;
  int d = blockIdx.x*4 + w;
  if (d >= N) return;
  int p = R[d], pend = R[d+1];
  float acc = first ? 0.f : aggr[(size_t)d*64 + lane];
  while (p < pend){
    int m = pend - p; if (m > 64) m = 64;
    int ev = (lane < m) ? ep[p + lane] : 0;
    for (int j = 0; j < m; ++j){
      int s = __shfl(ev, j);
      acc += tr[(size_t)s*64 + lane];
    }
    p += m;
  }
  aggr[(size_t)d*64 + lane] = acc;
}

// ---------- GRU update: h = (1-z)*n + z*h ----------
// block = 192 threads; thread j owns gate-row j; float4 loads; persistent grid
__global__ void k_gru(const float* __restrict__ aggr, float* __restrict__ h,
                      const float* __restrict__ wih, const float* __restrict__ whh,
                      const float* __restrict__ bih, const float* __restrict__ bhh, int N){
  int j = threadIdx.x;
  float4 wi4[16], wh4[16];
  const float4* wisrc = (const float4*)(wih + (size_t)j*64);
  const float4* whsrc = (const float4*)(whh + (size_t)j*64);
  #pragma unroll
  for (int c = 0; c < 16; ++c){ wi4[c] = wisrc[c]; wh4[c] = whsrc[c]; }
  float bi = bih[j], bh = bhh[j];
  __shared__ float gi_s[192], gh_s[192];
  for (int n = blockIdx.x; n < N; n += gridDim.x){
    const float4* mr = (const float4*)(aggr + (size_t)n*64);
    const float4* hr = (const float4*)(h + (size_t)n*64);
    float ai = bi, ah = bh;
    #pragma unroll
    for (int c = 0; c < 16; ++c){
      float4 m4 = mr[c], h4 = hr[c];
      ai = fmaf(m4.x, wi4[c].x, ai); ah = fmaf(h4.x, wh4[c].x, ah);
      ai = fmaf(m4.y, wi4[c].y, ai); ah = fmaf(h4.y, wh4[c].y, ah);
      ai = fmaf(m4.z, wi4[c].z, ai); ah = fmaf(h4.z, wh4[c].z, ah);
      ai = fmaf(m4.w, wi4[c].w, ai); ah = fmaf(h4.w, wh4[c].w, ah);
    }
    gi_s[j] = ai; gh_s[j] = ah;
    __syncthreads();
    if (j < 64){
      float r  = sigf(gi_s[j]      + gh_s[j]);
      float z  = sigf(gi_s[64+j]   + gh_s[64+j]);
      float nn = tanhf(gi_s[128+j] + r*gh_s[128+j]);
      h[(size_t)n*64 + j] = (1.f - z)*nn + z*h[(size_t)n*64 + j];
    }
    __syncthreads();
  }
}

// ---------- batch norm over nodes (64 channels, biased var) ----------
__global__ void k_bnstats(const float* __restrict__ h, float* __restrict__ stats, int N){
  int c = threadIdx.x & 63;
  int g = threadIdx.x >> 6;
  float s = 0.f, s2 = 0.f;
  for (int n = blockIdx.x*4 + g; n < N; n += gridDim.x*4){
    float v = h[(size_t)n*64 + c]; s += v; s2 += v*v;
  }
  __shared__ float sh[4][64], sh2[4][64];
  sh[g][c] = s; sh2[g][c] = s2;
  __syncthreads();
  if (g == 0){
    float ts = sh[0][c]+sh[1][c]+sh[2][c]+sh[3][c];
    float t2 = sh2[0][c]+sh2[1][c]+sh2[2][c]+sh2[3][c];
    atomicAdd(&stats[c], ts); atomicAdd(&stats[64+c], t2);
  }
}
__global__ void k_bnapply(float* __restrict__ h, const float* __restrict__ stats,
                          const float* __restrict__ g, const float* __restrict__ b,
                          int N, int relu){
  int i = blockIdx.x*blockDim.x + threadIdx.x;
  if (i >= N*64) return;
  int c = i & 63;
  float inv = 1.f/(float)N;
  float mean = stats[c]*inv;
  float var  = stats[64+c]*inv - mean*mean;
  float y = (h[i]-mean)*rsqrtf(var + 1e-5f)*g[c] + b[c];
  if (relu) y = fmaxf(y, 0.f);
  h[i] = y;
}

// ---------- avg_pool ----------
__global__ void k_pool_acc(const float* __restrict__ h, const int* __restrict__ asrc,
                           const int* __restrict__ adst, float* __restrict__ h2,
                           float* __restrict__ cnt, int A){
  int i = blockIdx.x*blockDim.x + threadIdx.x;
  if (i >= A*64) return;
  int a = i >> 6, c = i & 63;
  int s = asrc[a], d = adst[a];
  atomicAdd(&h2[(size_t)d*64 + c], h[(size_t)s*64 + c]);
  if (c == 0) atomicAdd(&cnt[d], 1.f);
}
__global__ void k_pool_div(float* __restrict__ h2, const float* __restrict__ cnt, int N){
  int i = blockIdx.x*blockDim.x + threadIdx.x;
  if (i >= N*64) return;
  h2[i] = h2[i] / fmaxf(cnt[i >> 6], 1.f);
}

// ---------- set2set ----------
__global__ void k_lstm(const float* __restrict__ inp, float* __restrict__ hv, float* __restrict__ cv,
                       const float* __restrict__ wih, const float* __restrict__ whh,
                       const float* __restrict__ bias, int IN){
  int b = blockIdx.x, j = threadIdx.x;
  __shared__ float is[128], hs[64], gs[256];
  if (j < IN) is[j] = inp[(size_t)b*IN + j];
  if (j < 64) hs[j] = hv[(size_t)b*64 + j];
  __syncthreads();
  float acc = bias[j];
  const float* wr = wih + (size_t)j*IN;
  for (int k = 0; k < IN; ++k) acc = fmaf(wr[k], is[k], acc);
  const float* w2 = whh + (size_t)j*64;
  #pragma unroll
  for (int k = 0; k < 64; ++k) acc = fmaf(w2[k], hs[k], acc);
  gs[j] = acc;
  __syncthreads();
  if (j < 64){
    float ig = sigf(gs[j]);
    float fg = sigf(gs[64+j]);
    float gg = tanhf(gs[128+j]);
    float og = sigf(gs[192+j]);
    float cn = fg*cv[(size_t)b*64+j] + ig*gg;
    cv[(size_t)b*64+j] = cn;
    hv[(size_t)b*64+j] = og*tanhf(cn);
  }
}
__global__ void k_attn_e(const float* __restrict__ x, const float* __restrict__ q,
                         const int* __restrict__ batch, float* __restrict__ e,
                         unsigned* __restrict__ emax, int N){
  int w = threadIdx.x >> 6, lane = threadIdx.x & 63;
  int n = blockIdx.x*4 + w;
  if (n >= N) return;
  int b = batch[n];
  float v = x[(size_t)n*64 + lane]*q[(size_t)b*64 + lane];
  for (int o = 32; o; o >>= 1) v += __shfl_down(v, o);
  if (lane == 0){ e[n] = v; atomicMax(&emax[b], fkey(v)); }
}
__global__ void k_attn_ex(const float* __restrict__ e, const unsigned* __restrict__ emax,
                          const int* __restrict__ batch, float* __restrict__ ex,
                          float* __restrict__ denom, int N){
  int n = blockIdx.x*blockDim.x + threadIdx.x;
  if (n >= N) return;
  int b = batch[n];
  float v = expf(e[n] - funkey(emax[b]));
  ex[n] = v;
  atomicAdd(&denom[b], v);
}
__global__ void k_qstar_prep(const float* __restrict__ h1, float* __restrict__ qstar){
  int i = blockIdx.x*blockDim.x + threadIdx.x;
  if (i >= 256*128) return;
  int b = i >> 7, c = i & 127;
  qstar[i] = (c < 64) ? h1[b*64 + c] : 0.f;
}
__global__ void k_attn_r(const float* __restrict__ x, const float* __restrict__ ex,
                         const float* __restrict__ denom, const int* __restrict__ batch,
                         float* __restrict__ qstar, int N){
  int w = threadIdx.x >> 6, lane = threadIdx.x & 63;
  int n = blockIdx.x*4 + w;
  if (n >= N) return;
  int b = batch[n];
  float a = ex[n]/denom[b];
  atomicAdd(&qstar[b*128 + 64 + lane], a*x[(size_t)n*64 + lane]);
}

// ---------- head ----------
__global__ void k_concat(const float* __restrict__ x1, const float* __restrict__ x2,
                         float* __restrict__ z){
  int i = blockIdx.x*blockDim.x + threadIdx.x;
  if (i >= 256*256) return;
  int b = i >> 8, c = i & 255;
  z[i] = (c < 128) ? x1[b*128 + c] : x2[b*128 + (c - 128)];
}
__global__ void k_bn_small(float* __restrict__ X, const float* __restrict__ g,
                           const float* __restrict__ b, int Bn, int F, int relu){
  int f = threadIdx.x;
  if (f >= F) return;
  float s = 0.f, s2 = 0.f;
  for (int i = 0; i < Bn; ++i){ float v = X[i*F + f]; s += v; s2 += v*v; }
  float mean = s/(float)Bn;
  float var  = s2/(float)Bn - mean*mean;
  float sc = rsqrtf(var + 1e-5f)*g[f];
  float bb = b[f];
  for (int i = 0; i < Bn; ++i){
    float y = (X[i*F + f] - mean)*sc + bb;
    if (relu) y = fmaxf(y, 0.f);
    X[i*F + f] = y;
  }
}
__global__ void k_fc(const float* __restrict__ X, const float* __restrict__ W,
                     const float* __restrict__ bias, float* __restrict__ Y, int K, int F){
  int b = blockIdx.x, f = threadIdx.x;
  if (f >= F) return;
  const float* xr = X + (size_t)b*K;
  const float* wr = W + (size_t)f*K;
  float acc = bias[f];
  for (int k = 0; k < K; ++k) acc = fmaf(xr[k], wr[k], acc);
  Y[b*F + f] = acc;
}
__global__ void k_fc_out(const float* __restrict__ z2, const float* __restrict__ w,
                         const float* __restrict__ bias, float* __restrict__ out){
  int b = blockIdx.x*blockDim.x + threadIdx.x;
  if (b >= 256) return;
  float acc = bias[0];
  #pragma unroll
  for (int k = 0; k < 64; ++k) acc = fmaf(z2[b*64 + k], w[k], acc);
  out[b] = acc;
}

extern "C" void kernel_launch(void* const* d_in, const int* in_sizes, int n_in,
                              void* d_out, int out_size, void* d_ws, size_t ws_size,
                              hipStream_t stream) {
  const float* x_in     = (const float*)d_in[0];
  const float* edge_attr= (const float*)d_in[1];
  const float* conv_w   = (const float*)d_in[2];   // [5][3][4][64][64]
  const float* conv_wih = (const float*)d_in[3];   // [5][192][64]
  const float* conv_whh = (const float*)d_in[4];
  const float* conv_bih = (const float*)d_in[5];   // [5][192]
  const float* conv_bhh = (const float*)d_in[6];
  const float* conv_nt  = (const float*)d_in[7];   // [5][9]
  const float* s1_wih0 = (const float*)d_in[8];
  const float* s1_whh0 = (const float*)d_in[9];
  const float* s1_b0   = (const float*)d_in[10];
  const float* s1_wih1 = (const float*)d_in[11];
  const float* s1_whh1 = (const float*)d_in[12];
  const float* s1_b1   = (const float*)d_in[13];
  const float* s2_wih0 = (const float*)d_in[14];
  const float* s2_whh0 = (const float*)d_in[15];
  const float* s2_b0   = (const float*)d_in[16];
  const float* s2_wih1 = (const float*)d_in[17];
  const float* s2_whh1 = (const float*)d_in[18];
  const float* s2_b1   = (const float*)d_in[19];
  const float* bn_g    = (const float*)d_in[20];
  const float* bn_b    = (const float*)d_in[21];
  const float* prebn_g = (const float*)d_in[22];
  const float* prebn_b = (const float*)d_in[23];
  const float* fc_w0   = (const float*)d_in[24];
  const float* fc_b0   = (const float*)d_in[25];
  const float* fc_w1   = (const float*)d_in[26];
  const float* fc_b1   = (const float*)d_in[27];
  const float* fc_w2   = (const float*)d_in[28];
  const float* fc_b2   = (const float*)d_in[29];
  const float* fcbn_g0 = (const float*)d_in[30];
  const float* fcbn_b0 = (const float*)d_in[31];
  const float* fcbn_g1 = (const float*)d_in[32];
  const float* fcbn_b1 = (const float*)d_in[33];
  const int* edge_index   = (const int*)d_in[34];
  const int* node_type    = (const int*)d_in[35];
  const int* batch        = (const int*)d_in[36];
  const int* assign_src   = (const int*)d_in[37];
  const int* assign_dst   = (const int*)d_in[38];
  const int* edge_index_2 = (const int*)d_in[39];
  const int* batch_2      = (const int*)d_in[40];
  (void)in_sizes; (void)n_in; (void)out_size; (void)ws_size;

  // ---- workspace layout, ~61 MB ----
  float* Wp = (float*)d_ws;
  size_t o = 0;
  auto alloc = [&](size_t n){ float* p = Wp + o; o += n; return p; };
  float*  h     = alloc((size_t)NN1*64);
  float*  tr    = alloc((size_t)NN1*64);
  float*  aggr  = alloc((size_t)NN1*64);
  float*  coeff = alloc(NN1);
  float*  h2    = alloc((size_t)NN2*64);
  float*  cnt   = alloc(NN2);
  float*  ebuf  = alloc(NN1);
  float*  exbuf = alloc(NN1);
  float*  qstar = alloc(256*128);   // qstar..cc1 contiguous: one memset
  float*  hh0   = alloc(256*64);
  float*  cc0   = alloc(256*64);
  float*  hh1   = alloc(256*64);
  float*  cc1   = alloc(256*64);
  unsigned* emaxu = (unsigned*)alloc(256);  // emaxu+denom contiguous
  float*  denom = alloc(256);
  float*  x1    = alloc(256*128);
  float*  x2    = alloc(256*128);
  float*  z     = alloc(256*256);
  float*  z1    = alloc(256*128);
  float*  z2    = alloc(256*64);
  float*  stats = alloc(128);
  int*    etype = (int*)alloc(EE1);
  int*    cnt1  = (int*)alloc(4*NN1);      // reused as cursor after scan
  int*    R1    = (int*)alloc(4*NN1 + 1);
  int*    ep1   = (int*)alloc(EE1);
  int*    cnt2  = (int*)alloc(NN2);        // reused as cursor
  int*    R2    = (int*)alloc(NN2 + 1);
  int*    ep2   = (int*)alloc(EE2);
  int*    csum  = (int*)alloc(1025);
  (void)o;

  const int* src1 = edge_index;
  const int* dst1 = edge_index + EE1;
  const int* src2 = edge_index_2;
  const int* dst2 = edge_index_2 + EE2;

  // ---- one-time per call: edge types + CSR structures ----
  k_etype<<<(EE1+255)/256, 256, 0, stream>>>(edge_attr, etype, EE1);
  k_copy<<<(NN1*64+255)/256, 256, 0, stream>>>(x_in, h, NN1*64);

  {  // level-1 CSR (4 types, flattened (t,d) rows)
    int M = 4*NN1, nchunk = (M + 1023)/1024;
    hipMemsetAsync(cnt1, 0, (size_t)M*sizeof(int), stream);
    k_hist<<<(EE1+255)/256, 256, 0, stream>>>(dst1, etype, cnt1, EE1, NN1);
    k_chunksum<<<nchunk, 256, 0, stream>>>(cnt1, csum, M);
    k_chunkscan<<<1, 1, 0, stream>>>(csum, nchunk);
    k_chunkapply<<<nchunk, 1, 0, stream>>>(cnt1, csum, R1, M);
    k_copyi<<<(M+255)/256, 256, 0, stream>>>(R1, cnt1, M);   // cnt1 becomes cursor
    k_scatter<<<(EE1+255)/256, 256, 0, stream>>>(src1, dst1, etype, cnt1, ep1, EE1, NN1);
  }
  {  // level-2 CSR (single type)
    int M = NN2, nchunk = (M + 1023)/1024;
    hipMemsetAsync(cnt2, 0, (size_t)M*sizeof(int), stream);
    k_hist<<<(EE2+255)/256, 256, 0, stream>>>(dst2, nullptr, cnt2, EE2, NN2);
    k_chunksum<<<nchunk, 256, 0, stream>>>(cnt2, csum, M);
    k_chunkscan<<<1, 1, 0, stream>>>(csum, nchunk);
    k_chunkapply<<<nchunk, 1, 0, stream>>>(cnt2, csum, R2, M);
    k_copyi<<<(M+255)/256, 256, 0, stream>>>(R2, cnt2, M);
    k_scatter<<<(EE2+255)/256, 256, 0, stream>>>(src2, dst2, nullptr, cnt2, ep2, EE2, NN2);
  }

  // ---- level-1: 3x MGGC(L=3) + BN + ReLU ----
  for (int i = 0; i < 3; ++i){
    k_coeff<<<(NN1+255)/256, 256, 0, stream>>>(conv_nt + i*9, node_type, coeff, NN1);
    for (int l = 0; l < 3; ++l){
      for (int t = 0; t < 4; ++t){
        k_transform<<<1024, 256, 0, stream>>>(h, conv_w + (size_t)((i*3+l)*4 + t)*4096, coeff, tr, NN1);
        k_sweep<<<(NN1+3)/4, 256, 0, stream>>>(tr, R1 + (size_t)t*NN1, ep1, aggr, NN1, t == 0);
      }
      k_gru<<<1024, 192, 0, stream>>>(aggr, h,
          conv_wih + (size_t)i*12288, conv_whh + (size_t)i*12288,
          conv_bih + i*192, conv_bhh + i*192, NN1);
    }
    hipMemsetAsync(stats, 0, 128*sizeof(float), stream);
    k_bnstats<<<256, 256, 0, stream>>>(h, stats, NN1);
    k_bnapply<<<(NN1*64+255)/256, 256, 0, stream>>>(h, stats, bn_g + i*64, bn_b + i*64, NN1, 1);
  }

  // ---- set2set helper ----
  auto set2set = [&](const float* xf, const int* bat, int Nn,
                     const float* wih0, const float* whh0, const float* b0,
                     const float* wih1, const float* whh1, const float* b1,
                     float* xout){
    hipMemsetAsync(qstar, 0, (size_t)(256*128 + 4*256*64)*sizeof(float), stream);
    for (int s = 0; s < 5; ++s){
      k_lstm<<<256, 256, 0, stream>>>(qstar, hh0, cc0, wih0, whh0, b0, 128);
      k_lstm<<<256, 256, 0, stream>>>(hh0, hh1, cc1, wih1, whh1, b1, 64);
      hipMemsetAsync(emaxu, 0, 2048, stream);
      k_attn_e<<<(Nn+3)/4, 256, 0, stream>>>(xf, hh1, bat, ebuf, emaxu, Nn);
      k_attn_ex<<<(Nn+255)/256, 256, 0, stream>>>(ebuf, emaxu, bat, exbuf, denom, Nn);
      k_qstar_prep<<<128, 256, 0, stream>>>(hh1, qstar);
      k_attn_r<<<(Nn+3)/4, 256, 0, stream>>>(xf, exbuf, denom, bat, qstar, Nn);
    }
    k_copy<<<128, 256, 0, stream>>>(qstar, xout, 256*128);
  };

  set2set(h, batch, NN1, s1_wih0, s1_whh0, s1_b0, s1_wih1, s1_whh1, s1_b1, x1);

  // ---- avg_pool to level 2 ----
  hipMemsetAsync(h2, 0, (size_t)NN2*64*sizeof(float), stream);
  hipMemsetAsync(cnt, 0, (size_t)NN2*sizeof(float), stream);
  k_pool_acc<<<(AA*64+255)/256, 256, 0, stream>>>(h, assign_src, assign_dst, h2, cnt, AA);
  k_pool_div<<<(NN2*64+255)/256, 256, 0, stream>>>(h2, cnt, NN2);

  // ---- level-2: 2x relu(MGGC(L=3)), single type, coeff=1 ----
  for (int L = 3; L < 5; ++L){
    for (int l = 0; l < 3; ++l){
      k_transform<<<1024, 256, 0, stream>>>(h2, conv_w + (size_t)((L*3+l)*4)*4096, nullptr, tr, NN2);
      k_sweep<<<(NN2+3)/4, 256, 0, stream>>>(tr, R2, ep2, aggr, NN2, 1);
      k_gru<<<1024, 192, 0, stream>>>(aggr, h2,
          conv_wih + (size_t)L*12288, conv_whh + (size_t)L*12288,
          conv_bih + L*192, conv_bhh + L*192, NN2);
    }
    k_relu<<<(NN2*64+255)/256, 256, 0, stream>>>(h2, NN2*64);
  }

  set2set(h2, batch_2, NN2, s2_wih0, s2_whh0, s2_b0, s2_wih1, s2_whh1, s2_b1, x2);

  // ---- head ----
  k_concat<<<256, 256, 0, stream>>>(x1, x2, z);
  k_bn_small<<<1, 256, 0, stream>>>(z, prebn_g, prebn_b, 256, 256, 0);
  k_fc<<<256, 128, 0, stream>>>(z, fc_w0, fc_b0, z1, 256, 128);
  k_bn_small<<<1, 128, 0, stream>>>(z1, fcbn_g0, fcbn_b0, 256, 128, 1);
  k_fc<<<256, 64, 0, stream>>>(z1, fc_w1, fc_b1, z2, 128, 64);
  k_bn_small<<<1, 64, 0, stream>>>(z2, fcbn_g1, fcbn_b1, 256, 64, 1);
  k_fc_out<<<4, 64, 0, stream>>>(z2, fc_w2, fc_b2, (float*)d_out);
}

// Round 5
// 6739.298 us; speedup vs baseline: 1.4901x; 1.1432x over previous
//
#include <hip/hip_runtime.h>

#define NN1 60000
#define EE1 600000
#define NN2 20000
#define EE2 150000
#define AA  60000

__device__ __forceinline__ float sigf(float x){ return 1.f/(1.f+expf(-x)); }
__device__ __forceinline__ unsigned fkey(float f){
  unsigned u = __float_as_uint(f);
  return (u & 0x80000000u) ? ~u : (u | 0x80000000u);
}
__device__ __forceinline__ float funkey(unsigned k){
  unsigned u = (k & 0x80000000u) ? (k ^ 0x80000000u) : ~k;
  return __uint_as_float(u);
}

// ---------- elementwise ----------
__global__ void k_relu(float* a, int n){
  int i = blockIdx.x*blockDim.x + threadIdx.x;
  if (i < n) a[i] = fmaxf(a[i], 0.f);
}
__global__ void k_copy(const float* __restrict__ a, float* __restrict__ o, int n){
  int i = blockIdx.x*blockDim.x + threadIdx.x;
  if (i < n) o[i] = a[i];
}

// ---------- edge type ----------
__global__ void k_etype(const float* __restrict__ ea, int* __restrict__ etype, int E){
  int e = blockIdx.x*blockDim.x + threadIdx.x;
  if (e >= E) return;
  const float* p = ea + (size_t)e*10;
  float best = p[0]; int bi = 0;
  #pragma unroll
  for (int k = 1; k < 4; ++k){ float v = p[k]; if (v > best){ best = v; bi = k; } }
  etype[e] = bi;
}

__global__ void k_coeff(const float* __restrict__ nt, const int* __restrict__ node_type,
                        float* __restrict__ coeff, int N){
  int n = blockIdx.x*blockDim.x + threadIdx.x;
  if (n < N) coeff[n] = nt[node_type[n]];
}

// ---------- CSR build ----------
// tkey=1: row = etype[e]*N + dst  (per-type rows); tkey=0: row = dst
__global__ void k_hist(const int* __restrict__ dst, const int* __restrict__ etype,
                       int* __restrict__ cnt, int E, int N, int tkey){
  int e = blockIdx.x*blockDim.x + threadIdx.x;
  if (e >= E) return;
  int t = etype ? etype[e] : 0;
  int key = tkey ? (t*N + dst[e]) : dst[e];
  atomicAdd(&cnt[key], 1);
}
// per-1024-chunk sums
__global__ void k_chunksum(const int* __restrict__ cnt, int* __restrict__ csum, int M){
  __shared__ int sh[256];
  int base = blockIdx.x*1024;
  int s = 0;
  for (int i = threadIdx.x; i < 1024; i += 256){
    int idx = base + i;
    if (idx < M) s += cnt[idx];
  }
  sh[threadIdx.x] = s;
  __syncthreads();
  for (int o = 128; o; o >>= 1){
    if (threadIdx.x < o) sh[threadIdx.x] += sh[threadIdx.x + o];
    __syncthreads();
  }
  if (threadIdx.x == 0) csum[blockIdx.x] = sh[0];
}
// exclusive scan of <=256 chunk sums, one block
__global__ void k_chunkscan(int* __restrict__ csum, int nchunk){
  __shared__ int sh[256];
  int i = threadIdx.x;
  int v = (i < nchunk) ? csum[i] : 0;
  sh[i] = v; __syncthreads();
  for (int o = 1; o < 256; o <<= 1){
    int y = (i >= o) ? sh[i-o] : 0;
    __syncthreads();
    sh[i] += y;
    __syncthreads();
  }
  if (i < nchunk) csum[i] = sh[i] - v;   // exclusive
  if (i == 255) csum[nchunk] = sh[255];  // total
}
// per-chunk exclusive scan -> R, also write cursor copy; last block writes R[M]
__global__ void k_chunkapply(const int* __restrict__ cnt, const int* __restrict__ csum,
                             int* __restrict__ R, int* __restrict__ cur, int M){
  __shared__ int sh[256];
  int base = blockIdx.x*1024;
  int i0 = base + threadIdx.x*4;
  int v[4]; int s = 0;
  #pragma unroll
  for (int k = 0; k < 4; ++k){ int idx = i0 + k; v[k] = (idx < M) ? cnt[idx] : 0; s += v[k]; }
  sh[threadIdx.x] = s; __syncthreads();
  for (int o = 1; o < 256; o <<= 1){
    int y = (threadIdx.x >= o) ? sh[threadIdx.x-o] : 0;
    __syncthreads();
    sh[threadIdx.x] += y;
    __syncthreads();
  }
  int run = csum[blockIdx.x] + sh[threadIdx.x] - s;
  #pragma unroll
  for (int k = 0; k < 4; ++k){
    int idx = i0 + k;
    if (idx < M){ R[idx] = run; cur[idx] = run; run += v[k]; }
  }
  if (threadIdx.x == 255 && base + 1024 >= M) R[M] = csum[blockIdx.x] + sh[255];
}
// entries always packed (t<<20)|src
__global__ void k_scatter(const int* __restrict__ src, const int* __restrict__ dst,
                          const int* __restrict__ etype, int* __restrict__ cur,
                          int* __restrict__ ep, int E, int N, int tkey){
  int e = blockIdx.x*blockDim.x + threadIdx.x;
  if (e >= E) return;
  int t = etype ? etype[e] : 0;
  int key = tkey ? (t*N + dst[e]) : dst[e];
  int pos = atomicAdd(&cur[key], 1);
  ep[pos] = (t << 20) | src[e];
}

// ---------- transform: tr[t][n][d] = coeff[n] * sum_c h[n][c]*W[t][c][d] ----------
// grid = T*1024 blocks; block handles one type; 64 weight VGPRs/thread
__global__ void k_transform4(const float* __restrict__ h, const float* __restrict__ W,
                             const float* __restrict__ coeff, float* __restrict__ tr, int N){
  int t = blockIdx.x >> 10, blk = blockIdx.x & 1023;
  int d = threadIdx.x & 63, sub = threadIdx.x >> 6;
  float wreg[64];
  const float* Wt = W + (size_t)t*4096;
  #pragma unroll
  for (int c = 0; c < 64; ++c) wreg[c] = Wt[c*64 + d];
  for (int n = blk*4 + sub; n < N; n += 4096){
    const float4* hr = (const float4*)(h + (size_t)n*64);
    float acc = 0.f;
    #pragma unroll
    for (int c = 0; c < 16; ++c){
      float4 v = hr[c];
      acc = fmaf(v.x, wreg[4*c+0], acc);
      acc = fmaf(v.y, wreg[4*c+1], acc);
      acc = fmaf(v.z, wreg[4*c+2], acc);
      acc = fmaf(v.w, wreg[4*c+3], acc);
    }
    if (coeff) acc *= coeff[n];
    tr[((size_t)t*N + n)*64 + d] = acc;
  }
}

// ---------- merged sweep: one wave per dst row; packed (t,src) entries ----------
__global__ void k_sweep_p(const float* __restrict__ tr, const int* __restrict__ R,
                          const int* __restrict__ ep, float* __restrict__ aggr, int N){
  int w = threadIdx.x >> 6, lane = threadIdx.x & 63;
  int d = blockIdx.x*4 + w;
  if (d >= N) return;
  int p = R[d], pend = R[d+1];
  float acc = 0.f;
  while (p < pend){
    int m = pend - p; if (m > 64) m = 64;
    int ev = (lane < m) ? ep[p + lane] : 0;
    for (int j = 0; j < m; ++j){
      int pk = __shfl(ev, j);
      int s = pk & 0xFFFFF, t = pk >> 20;
      acc += tr[((size_t)t*N + s)*64 + lane];
    }
    p += m;
  }
  aggr[(size_t)d*64 + lane] = acc;
}
// per-type sweep (fallback path): row offset pre-applied in R, single tr buffer
__global__ void k_sweep(const float* __restrict__ tr, const int* __restrict__ R,
                        const int* __restrict__ ep, float* __restrict__ aggr,
                        int N, int first){
  int w = threadIdx.x >> 6, lane = threadIdx.x & 63;
  int d = blockIdx.x*4 + w;
  if (d >= N) return;
  int p = R[d], pend = R[d+1];
  float acc = first ? 0.f : aggr[(size_t)d*64 + lane];
  while (p < pend){
    int m = pend - p; if (m > 64) m = 64;
    int ev = (lane < m) ? ep[p + lane] : 0;
    for (int j = 0; j < m; ++j){
      int s = __shfl(ev, j) & 0xFFFFF;
      acc += tr[(size_t)s*64 + lane];
    }
    p += m;
  }
  aggr[(size_t)d*64 + lane] = acc;
}

// ---------- GRU ----------
__global__ void k_gru(const float* __restrict__ aggr, float* __restrict__ h,
                      const float* __restrict__ wih, const float* __restrict__ whh,
                      const float* __restrict__ bih, const float* __restrict__ bhh, int N){
  int j = threadIdx.x;
  float4 wi4[16], wh4[16];
  const float4* wisrc = (const float4*)(wih + (size_t)j*64);
  const float4* whsrc = (const float4*)(whh + (size_t)j*64);
  #pragma unroll
  for (int c = 0; c < 16; ++c){ wi4[c] = wisrc[c]; wh4[c] = whsrc[c]; }
  float bi = bih[j], bh = bhh[j];
  __shared__ float gi_s[192], gh_s[192];
  for (int n = blockIdx.x; n < N; n += gridDim.x){
    const float4* mr = (const float4*)(aggr + (size_t)n*64);
    const float4* hr = (const float4*)(h + (size_t)n*64);
    float ai = bi, ah = bh;
    #pragma unroll
    for (int c = 0; c < 16; ++c){
      float4 m4 = mr[c], h4 = hr[c];
      ai = fmaf(m4.x, wi4[c].x, ai); ah = fmaf(h4.x, wh4[c].x, ah);
      ai = fmaf(m4.y, wi4[c].y, ai); ah = fmaf(h4.y, wh4[c].y, ah);
      ai = fmaf(m4.z, wi4[c].z, ai); ah = fmaf(h4.z, wh4[c].z, ah);
      ai = fmaf(m4.w, wi4[c].w, ai); ah = fmaf(h4.w, wh4[c].w, ah);
    }
    gi_s[j] = ai; gh_s[j] = ah;
    __syncthreads();
    if (j < 64){
      float r  = sigf(gi_s[j]      + gh_s[j]);
      float z  = sigf(gi_s[64+j]   + gh_s[64+j]);
      float nn = tanhf(gi_s[128+j] + r*gh_s[128+j]);
      h[(size_t)n*64 + j] = (1.f - z)*nn + z*h[(size_t)n*64 + j];
    }
    __syncthreads();
  }
}

// ---------- batch norm over nodes ----------
__global__ void k_bnstats(const float* __restrict__ h, float* __restrict__ stats, int N){
  int c = threadIdx.x & 63;
  int g = threadIdx.x >> 6;
  float s = 0.f, s2 = 0.f;
  for (int n = blockIdx.x*4 + g; n < N; n += gridDim.x*4){
    float v = h[(size_t)n*64 + c]; s += v; s2 += v*v;
  }
  __shared__ float sh[4][64], sh2[4][64];
  sh[g][c] = s; sh2[g][c] = s2;
  __syncthreads();
  if (g == 0){
    float ts = sh[0][c]+sh[1][c]+sh[2][c]+sh[3][c];
    float t2 = sh2[0][c]+sh2[1][c]+sh2[2][c]+sh2[3][c];
    atomicAdd(&stats[c], ts); atomicAdd(&stats[64+c], t2);
  }
}
__global__ void k_bnapply(float* __restrict__ h, const float* __restrict__ stats,
                          const float* __restrict__ g, const float* __restrict__ b,
                          int N, int relu){
  int i = blockIdx.x*blockDim.x + threadIdx.x;
  if (i >= N*64) return;
  int c = i & 63;
  float inv = 1.f/(float)N;
  float mean = stats[c]*inv;
  float var  = stats[64+c]*inv - mean*mean;
  float y = (h[i]-mean)*rsqrtf(var + 1e-5f)*g[c] + b[c];
  if (relu) y = fmaxf(y, 0.f);
  h[i] = y;
}

// ---------- avg_pool ----------
__global__ void k_pool_acc(const float* __restrict__ h, const int* __restrict__ asrc,
                           const int* __restrict__ adst, float* __restrict__ h2,
                           float* __restrict__ cnt, int A){
  int i = blockIdx.x*blockDim.x + threadIdx.x;
  if (i >= A*64) return;
  int a = i >> 6, c = i & 63;
  int s = asrc[a], d = adst[a];
  atomicAdd(&h2[(size_t)d*64 + c], h[(size_t)s*64 + c]);
  if (c == 0) atomicAdd(&cnt[d], 1.f);
}
__global__ void k_pool_div(float* __restrict__ h2, const float* __restrict__ cnt, int N){
  int i = blockIdx.x*blockDim.x + threadIdx.x;
  if (i >= N*64) return;
  h2[i] = h2[i] / fmaxf(cnt[i >> 6], 1.f);
}

// ---------- set2set: both LSTM cells fused; also resets emax/denom ----------
__global__ void k_lstm2(const float* __restrict__ qstar,
                        float* __restrict__ h0, float* __restrict__ c0,
                        float* __restrict__ h1, float* __restrict__ c1,
                        const float* __restrict__ wih0, const float* __restrict__ whh0,
                        const float* __restrict__ b0,
                        const float* __restrict__ wih1, const float* __restrict__ whh1,
                        const float* __restrict__ b1,
                        unsigned* __restrict__ emaxu, float* __restrict__ denom){
  int b = blockIdx.x, j = threadIdx.x;
  __shared__ float is[128], hs0[64], h1p[64], h0n[64], gs[256];
  if (j < 128) is[j] = qstar[(size_t)b*128 + j];
  else if (j < 192) hs0[j-128] = h0[(size_t)b*64 + (j-128)];
  else h1p[j-192] = h1[(size_t)b*64 + (j-192)];
  if (j == 0){ emaxu[b] = 0u; denom[b] = 0.f; }
  __syncthreads();
  // LSTM0: input 128 = qstar, hidden 64
  float acc = b0[j];
  const float* wr = wih0 + (size_t)j*128;
  #pragma unroll 8
  for (int k = 0; k < 128; ++k) acc = fmaf(wr[k], is[k], acc);
  const float* w2 = whh0 + (size_t)j*64;
  #pragma unroll 8
  for (int k = 0; k < 64; ++k) acc = fmaf(w2[k], hs0[k], acc);
  gs[j] = acc;
  __syncthreads();
  if (j < 64){
    float ig = sigf(gs[j]);
    float fg = sigf(gs[64+j]);
    float gg = tanhf(gs[128+j]);
    float og = sigf(gs[192+j]);
    float cn = fg*c0[(size_t)b*64+j] + ig*gg;
    c0[(size_t)b*64+j] = cn;
    float hn = og*tanhf(cn);
    h0[(size_t)b*64+j] = hn;
    h0n[j] = hn;
  }
  __syncthreads();
  // LSTM1: input 64 = new h0, hidden 64
  acc = b1[j];
  const float* wr1 = wih1 + (size_t)j*64;
  #pragma unroll 8
  for (int k = 0; k < 64; ++k) acc = fmaf(wr1[k], h0n[k], acc);
  const float* w21 = whh1 + (size_t)j*64;
  #pragma unroll 8
  for (int k = 0; k < 64; ++k) acc = fmaf(w21[k], h1p[k], acc);
  gs[j] = acc;
  __syncthreads();
  if (j < 64){
    float ig = sigf(gs[j]);
    float fg = sigf(gs[64+j]);
    float gg = tanhf(gs[128+j]);
    float og = sigf(gs[192+j]);
    float cn = fg*c1[(size_t)b*64+j] + ig*gg;
    c1[(size_t)b*64+j] = cn;
    h1[(size_t)b*64+j] = og*tanhf(cn);
  }
}
__global__ void k_attn_e(const float* __restrict__ x, const float* __restrict__ q,
                         const int* __restrict__ batch, float* __restrict__ e,
                         unsigned* __restrict__ emax, int N){
  int w = threadIdx.x >> 6, lane = threadIdx.x & 63;
  int n = blockIdx.x*4 + w;
  if (n >= N) return;
  int b = batch[n];
  float v = x[(size_t)n*64 + lane]*q[(size_t)b*64 + lane];
  for (int o = 32; o; o >>= 1) v += __shfl_down(v, o);
  if (lane == 0){ e[n] = v; atomicMax(&emax[b], fkey(v)); }
}
// blocks [0,nbex): exp/denom; blocks [nbex, nbex+128): qstar prep (q part + zero r part)
__global__ void k_attn_exprep(const float* __restrict__ e, const unsigned* __restrict__ emax,
                              const int* __restrict__ batch, float* __restrict__ ex,
                              float* __restrict__ denom,
                              const float* __restrict__ h1, float* __restrict__ qstar,
                              int N, int nbex){
  if ((int)blockIdx.x < nbex){
    int n = blockIdx.x*256 + threadIdx.x;
    if (n >= N) return;
    int b = batch[n];
    float v = expf(e[n] - funkey(emax[b]));
    ex[n] = v;
    atomicAdd(&denom[b], v);
  } else {
    int i = (blockIdx.x - nbex)*256 + threadIdx.x;  // 0..32767
    int b = i >> 7, c = i & 127;
    qstar[i] = (c < 64) ? h1[(size_t)b*64 + c] : 0.f;
  }
}
__global__ void k_attn_r(const float* __restrict__ x, const float* __restrict__ ex,
                         const float* __restrict__ denom, const int* __restrict__ batch,
                         float* __restrict__ qstar, int N){
  int w = threadIdx.x >> 6, lane = threadIdx.x & 63;
  int n = blockIdx.x*4 + w;
  if (n >= N) return;
  int b = batch[n];
  float a = ex[n]/denom[b];
  atomicAdd(&qstar[(size_t)b*128 + 64 + lane], a*x[(size_t)n*64 + lane]);
}

// ---------- head ----------
__global__ void k_concat(const float* __restrict__ x1, const float* __restrict__ x2,
                         float* __restrict__ z){
  int i = blockIdx.x*blockDim.x + threadIdx.x;
  if (i >= 256*256) return;
  int b = i >> 8, c = i & 255;
  z[i] = (c < 128) ? x1[b*128 + c] : x2[b*128 + (c - 128)];
}
// one block per feature, Bn=256 rows
__global__ void k_bn_par(float* __restrict__ X, const float* __restrict__ g,
                         const float* __restrict__ b, int F, int relu){
  int f = blockIdx.x, i = threadIdx.x;
  float v = X[(size_t)i*F + f];
  __shared__ float s1[256], s2[256];
  s1[i] = v; s2[i] = v*v;
  __syncthreads();
  for (int o = 128; o; o >>= 1){
    if (i < o){ s1[i] += s1[i+o]; s2[i] += s2[i+o]; }
    __syncthreads();
  }
  float mean = s1[0]*(1.f/256.f);
  float var  = s2[0]*(1.f/256.f) - mean*mean;
  float y = (v - mean)*rsqrtf(var + 1e-5f)*g[f] + b[f];
  if (relu) y = fmaxf(y, 0.f);
  X[(size_t)i*F + f] = y;
}
__global__ void k_fc(const float* __restrict__ X, const float* __restrict__ W,
                     const float* __restrict__ bias, float* __restrict__ Y, int K, int F){
  int b = blockIdx.x, f = threadIdx.x;
  if (f >= F) return;
  const float* xr = X + (size_t)b*K;
  const float* wr = W + (size_t)f*K;
  float acc = bias[f];
  for (int k = 0; k < K; ++k) acc = fmaf(xr[k], wr[k], acc);
  Y[(size_t)b*F + f] = acc;
}
__global__ void k_fc_out(const float* __restrict__ z2, const float* __restrict__ w,
                         const float* __restrict__ bias, float* __restrict__ out){
  int b = blockIdx.x*blockDim.x + threadIdx.x;
  if (b >= 256) return;
  float acc = bias[0];
  #pragma unroll
  for (int k = 0; k < 64; ++k) acc = fmaf(z2[b*64 + k], w[k], acc);
  out[b] = acc;
}

extern "C" void kernel_launch(void* const* d_in, const int* in_sizes, int n_in,
                              void* d_out, int out_size, void* d_ws, size_t ws_size,
                              hipStream_t stream) {
  const float* x_in     = (const float*)d_in[0];
  const float* edge_attr= (const float*)d_in[1];
  const float* conv_w   = (const float*)d_in[2];
  const float* conv_wih = (const float*)d_in[3];
  const float* conv_whh = (const float*)d_in[4];
  const float* conv_bih = (const float*)d_in[5];
  const float* conv_bhh = (const float*)d_in[6];
  const float* conv_nt  = (const float*)d_in[7];
  const float* s1_wih0 = (const float*)d_in[8];
  const float* s1_whh0 = (const float*)d_in[9];
  const float* s1_b0   = (const float*)d_in[10];
  const float* s1_wih1 = (const float*)d_in[11];
  const float* s1_whh1 = (const float*)d_in[12];
  const float* s1_b1   = (const float*)d_in[13];
  const float* s2_wih0 = (const float*)d_in[14];
  const float* s2_whh0 = (const float*)d_in[15];
  const float* s2_b0   = (const float*)d_in[16];
  const float* s2_wih1 = (const float*)d_in[17];
  const float* s2_whh1 = (const float*)d_in[18];
  const float* s2_b1   = (const float*)d_in[19];
  const float* bn_g    = (const float*)d_in[20];
  const float* bn_b    = (const float*)d_in[21];
  const float* prebn_g = (const float*)d_in[22];
  const float* prebn_b = (const float*)d_in[23];
  const float* fc_w0   = (const float*)d_in[24];
  const float* fc_b0   = (const float*)d_in[25];
  const float* fc_w1   = (const float*)d_in[26];
  const float* fc_b1   = (const float*)d_in[27];
  const float* fc_w2   = (const float*)d_in[28];
  const float* fc_b2   = (const float*)d_in[29];
  const float* fcbn_g0 = (const float*)d_in[30];
  const float* fcbn_b0 = (const float*)d_in[31];
  const float* fcbn_g1 = (const float*)d_in[32];
  const float* fcbn_b1 = (const float*)d_in[33];
  const int* edge_index   = (const int*)d_in[34];
  const int* node_type    = (const int*)d_in[35];
  const int* batch        = (const int*)d_in[36];
  const int* assign_src   = (const int*)d_in[37];
  const int* assign_dst   = (const int*)d_in[38];
  const int* edge_index_2 = (const int*)d_in[39];
  const int* batch_2      = (const int*)d_in[40];
  (void)in_sizes; (void)n_in; (void)out_size;

  // ---- workspace layout; tr4 size chosen from ws_size (constant across calls) ----
  float* Wp = (float*)d_ws;
  float *h, *tr, *aggr, *coeff, *h2, *cnt, *ebuf, *exbuf, *qstar, *hh0, *cc0, *hh1, *cc1;
  unsigned* emaxu; float *denom, *x1, *x2, *z, *z1, *z2, *stats;
  int *etype, *cnt1, *R1, *ep1, *cnt2, *R2, *ep2, *csum;
  size_t o = 0;
  auto layout = [&](size_t trsize){
    o = 0;
    auto alloc = [&](size_t n){ float* p = Wp + o; o += n; return p; };
    h     = alloc((size_t)NN1*64);
    tr    = alloc(trsize);
    aggr  = alloc((size_t)NN1*64);
    coeff = alloc(NN1);
    h2    = alloc((size_t)NN2*64);
    cnt   = alloc(NN2);
    ebuf  = alloc(NN1);
    exbuf = alloc(NN1);
    qstar = alloc(256*128);
    hh0   = alloc(256*64);
    cc0   = alloc(256*64);
    hh1   = alloc(256*64);
    cc1   = alloc(256*64);
    emaxu = (unsigned*)alloc(256);
    denom = alloc(256);
    x1    = alloc(256*128);
    x2    = alloc(256*128);
    z     = alloc(256*256);
    z1    = alloc(256*128);
    z2    = alloc(256*64);
    stats = alloc(128);
    etype = (int*)alloc(EE1);
    cnt1  = (int*)alloc(4*NN1);
    R1    = (int*)alloc(4*NN1 + 1);
    ep1   = (int*)alloc(EE1);
    cnt2  = (int*)alloc(NN2);
    R2    = (int*)alloc(NN2 + 1);
    ep2   = (int*)alloc(EE2);
    csum  = (int*)alloc(260);
  };
  layout((size_t)4*NN1*64);
  int bigpath = (o*sizeof(float) <= ws_size);
  if (!bigpath) layout((size_t)NN1*64);

  const int* src1 = edge_index;
  const int* dst1 = edge_index + EE1;
  const int* src2 = edge_index_2;
  const int* dst2 = edge_index_2 + EE2;

  k_etype<<<(EE1+255)/256, 256, 0, stream>>>(edge_attr, etype, EE1);
  k_copy<<<(NN1*64+255)/256, 256, 0, stream>>>(x_in, h, NN1*64);

  {  // level-1 CSR: dst-keyed (big) or (t,dst)-keyed (small)
    int M = bigpath ? NN1 : 4*NN1;
    int nchunk = (M + 1023)/1024;
    hipMemsetAsync(cnt1, 0, (size_t)M*sizeof(int), stream);
    k_hist<<<(EE1+255)/256, 256, 0, stream>>>(dst1, etype, cnt1, EE1, NN1, !bigpath);
    k_chunksum<<<nchunk, 256, 0, stream>>>(cnt1, csum, M);
    k_chunkscan<<<1, 256, 0, stream>>>(csum, nchunk);
    k_chunkapply<<<nchunk, 256, 0, stream>>>(cnt1, csum, R1, cnt1, M);
    k_scatter<<<(EE1+255)/256, 256, 0, stream>>>(src1, dst1, etype, cnt1, ep1, EE1, NN1, !bigpath);
  }
  {  // level-2 CSR: dst-keyed, single type
    int M = NN2, nchunk = (M + 1023)/1024;
    hipMemsetAsync(cnt2, 0, (size_t)M*sizeof(int), stream);
    k_hist<<<(EE2+255)/256, 256, 0, stream>>>(dst2, nullptr, cnt2, EE2, NN2, 0);
    k_chunksum<<<nchunk, 256, 0, stream>>>(cnt2, csum, M);
    k_chunkscan<<<1, 256, 0, stream>>>(csum, nchunk);
    k_chunkapply<<<nchunk, 256, 0, stream>>>(cnt2, csum, R2, cnt2, M);
    k_scatter<<<(EE2+255)/256, 256, 0, stream>>>(src2, dst2, nullptr, cnt2, ep2, EE2, NN2, 0);
  }

  // ---- level-1: 3x MGGC(L=3) + BN + ReLU ----
  for (int i = 0; i < 3; ++i){
    k_coeff<<<(NN1+255)/256, 256, 0, stream>>>(conv_nt + i*9, node_type, coeff, NN1);
    for (int l = 0; l < 3; ++l){
      const float* Wl = conv_w + (size_t)(i*3+l)*4*4096;
      if (bigpath){
        k_transform4<<<4096, 256, 0, stream>>>(h, Wl, coeff, tr, NN1);
        k_sweep_p<<<(NN1+3)/4, 256, 0, stream>>>(tr, R1, ep1, aggr, NN1);
      } else {
        for (int t = 0; t < 4; ++t){
          k_transform4<<<1024, 256, 0, stream>>>(h, Wl + (size_t)t*4096, coeff, tr, NN1);
          k_sweep<<<(NN1+3)/4, 256, 0, stream>>>(tr, R1 + (size_t)t*NN1, ep1, aggr, NN1, t == 0);
        }
      }
      k_gru<<<1024, 192, 0, stream>>>(aggr, h,
          conv_wih + (size_t)i*12288, conv_whh + (size_t)i*12288,
          conv_bih + i*192, conv_bhh + i*192, NN1);
    }
    hipMemsetAsync(stats, 0, 128*sizeof(float), stream);
    k_bnstats<<<256, 256, 0, stream>>>(h, stats, NN1);
    k_bnapply<<<(NN1*64+255)/256, 256, 0, stream>>>(h, stats, bn_g + i*64, bn_b + i*64, NN1, 1);
  }

  // ---- set2set ----
  auto set2set = [&](const float* xf, const int* bat, int Nn,
                     const float* wih0, const float* whh0, const float* b0,
                     const float* wih1, const float* whh1, const float* b1,
                     float* xout){
    hipMemsetAsync(qstar, 0, (size_t)(256*128 + 4*256*64)*sizeof(float), stream);
    int nbex = (Nn + 255)/256;
    for (int s = 0; s < 5; ++s){
      k_lstm2<<<256, 256, 0, stream>>>(qstar, hh0, cc0, hh1, cc1,
                                       wih0, whh0, b0, wih1, whh1, b1, emaxu, denom);
      k_attn_e<<<(Nn+3)/4, 256, 0, stream>>>(xf, hh1, bat, ebuf, emaxu, Nn);
      k_attn_exprep<<<nbex + 128, 256, 0, stream>>>(ebuf, emaxu, bat, exbuf, denom, hh1, qstar, Nn, nbex);
      k_attn_r<<<(Nn+3)/4, 256, 0, stream>>>(xf, exbuf, denom, bat, qstar, Nn);
    }
    k_copy<<<128, 256, 0, stream>>>(qstar, xout, 256*128);
  };

  set2set(h, batch, NN1, s1_wih0, s1_whh0, s1_b0, s1_wih1, s1_whh1, s1_b1, x1);

  // ---- avg_pool ----
  hipMemsetAsync(h2, 0, (size_t)NN2*64*sizeof(float), stream);
  hipMemsetAsync(cnt, 0, (size_t)NN2*sizeof(float), stream);
  k_pool_acc<<<(AA*64+255)/256, 256, 0, stream>>>(h, assign_src, assign_dst, h2, cnt, AA);
  k_pool_div<<<(NN2*64+255)/256, 256, 0, stream>>>(h2, cnt, NN2);

  // ---- level-2: 2x relu(MGGC(L=3)), single type ----
  for (int L = 3; L < 5; ++L){
    for (int l = 0; l < 3; ++l){
      k_transform4<<<1024, 256, 0, stream>>>(h2, conv_w + (size_t)(L*3+l)*4*4096, nullptr, tr, NN2);
      k_sweep_p<<<(NN2+3)/4, 256, 0, stream>>>(tr, R2, ep2, aggr, NN2);
      k_gru<<<1024, 192, 0, stream>>>(aggr, h2,
          conv_wih + (size_t)L*12288, conv_whh + (size_t)L*12288,
          conv_bih + L*192, conv_bhh + L*192, NN2);
    }
    k_relu<<<(NN2*64+255)/256, 256, 0, stream>>>(h2, NN2*64);
  }

  set2set(h2, batch_2, NN2, s2_wih0, s2_whh0, s2_b0, s2_wih1, s2_whh1, s2_b1, x2);

  // ---- head ----
  k_concat<<<256, 256, 0, stream>>>(x1, x2, z);
  k_bn_par<<<256, 256, 0, stream>>>(z, prebn_g, prebn_b, 256, 0);
  k_fc<<<256, 128, 0, stream>>>(z, fc_w0, fc_b0, z1, 256, 128);
  k_bn_par<<<128, 256, 0, stream>>>(z1, fcbn_g0, fcbn_b0, 128, 1);
  k_fc<<<256, 64, 0, stream>>>(z1, fc_w1, fc_b1, z2, 128, 64);
  k_bn_par<<<64, 256, 0, stream>>>(z2, fcbn_g1, fcbn_b1, 64, 1);
  k_fc_out<<<4, 64, 0, stream>>>(z2, fc_w2, fc_b2, (float*)d_out);
}